// Round 8
// baseline (227.191 us; speedup 1.0000x reference)
//
#include <hip/hip_runtime.h>
#include <hip/hip_bf16.h>
#include <stdint.h>

typedef __bf16 bf16_t;
typedef float floatx4 __attribute__((ext_vector_type(4)));
typedef __bf16 bf16x8 __attribute__((ext_vector_type(8)));
typedef __bf16 bf16x4 __attribute__((ext_vector_type(4)));

// scale = DH^-0.5 * log2(e), folded into Q at GEMM epilogue so softmax uses raw exp2
#define QSCALE 0.1803368801111204f

// -------------------- async global->LDS (16B) --------------------
__device__ __forceinline__ void gl2lds16(const bf16_t* g, bf16_t* l) {
    __builtin_amdgcn_global_load_lds(
        (const __attribute__((address_space(1))) unsigned int*)g,
        (__attribute__((address_space(3))) unsigned int*)l,
        16, 0, 0);
}

// -------------------- fused convert + QKV projection GEMM (R7, unchanged) ------
__global__ __launch_bounds__(256) void qkv_gemm(const float* __restrict__ X,    // [8192][512] fp32
                                                const float* __restrict__ W,    // [1536][512] fp32
                                                bf16_t* __restrict__ Q,         // [32][2048][64] (pre-scaled)
                                                bf16_t* __restrict__ K,         // [32][2048][64]
                                                bf16_t* __restrict__ Vt)        // [32][64][2048]
{
    __shared__ bf16_t As[128 * 64];
    __shared__ bf16_t Bs[128 * 64];

    const int tid  = threadIdx.x;
    const int wave = tid >> 6;
    const int lane = tid & 63;
    const int quad = lane >> 4;
    const int lrow = lane & 15;
    const int t7g  = lrow & 7;
    const int bm0 = blockIdx.x * 128;
    const int bn0 = blockIdx.y * 128;
    const int mw = (wave >> 1) * 64;
    const int nw = (wave & 1) * 64;

    floatx4 acc[4][4];
#pragma unroll
    for (int i = 0; i < 4; i++)
#pragma unroll
        for (int j = 0; j < 4; j++) acc[i][j] = (floatx4)0.0f;

#pragma unroll 1
    for (int kb = 0; kb < 8; ++kb) {
        const int k0 = kb * 64;
        __syncthreads();
#pragma unroll
        for (int r = 0; r < 4; ++r) {
            int ch = r * 256 + tid;            // chunk 0..1023 (8 bf16 each)
            int row = ch >> 3, kc = ch & 7;
            int skc = kc ^ (row & 7);
            const float* src = X + (size_t)(bm0 + row) * 512 + k0 + skc * 8;
            float4 a = *(const float4*)src;
            float4 bq = *(const float4*)(src + 4);
            bf16x8 v = {(bf16_t)a.x,(bf16_t)a.y,(bf16_t)a.z,(bf16_t)a.w,
                        (bf16_t)bq.x,(bf16_t)bq.y,(bf16_t)bq.z,(bf16_t)bq.w};
            *(bf16x8*)(As + (size_t)ch * 8) = v;
        }
#pragma unroll
        for (int r = 0; r < 4; ++r) {
            int ch = r * 256 + tid;
            int row = ch >> 3, kc = ch & 7;
            int skc = kc ^ (row & 7);
            const float* src = W + (size_t)(bn0 + row) * 512 + k0 + skc * 8;
            float4 a = *(const float4*)src;
            float4 bq = *(const float4*)(src + 4);
            bf16x8 v = {(bf16_t)a.x,(bf16_t)a.y,(bf16_t)a.z,(bf16_t)a.w,
                        (bf16_t)bq.x,(bf16_t)bq.y,(bf16_t)bq.z,(bf16_t)bq.w};
            *(bf16x8*)(Bs + (size_t)ch * 8) = v;
        }
        __syncthreads();
#pragma unroll
        for (int ks = 0; ks < 2; ++ks) {
            bf16x8 af[4], bfr[4];
#pragma unroll
            for (int mi = 0; mi < 4; mi++)
                af[mi] = *(const bf16x8*)(As + (mw + mi * 16 + lrow) * 64 + (((ks * 4 + quad) ^ t7g) << 3));
#pragma unroll
            for (int ni = 0; ni < 4; ni++)
                bfr[ni] = *(const bf16x8*)(Bs + (nw + ni * 16 + lrow) * 64 + (((ks * 4 + quad) ^ t7g) << 3));
#pragma unroll
            for (int mi = 0; mi < 4; mi++)
#pragma unroll
                for (int ni = 0; ni < 4; ni++)
                    acc[mi][ni] = __builtin_amdgcn_mfma_f32_16x16x32_bf16(af[mi], bfr[ni], acc[mi][ni], 0, 0, 0);
        }
    }

    // epilogue: C/D layout col=lane&15, row=quad*4+reg  [verified m89]
#pragma unroll
    for (int mi = 0; mi < 4; mi++) {
        int mbase = bm0 + mw + mi * 16 + quad * 4;
        int b = mbase >> 11, n = mbase & 2047;
#pragma unroll
        for (int ni = 0; ni < 4; ni++) {
            int o = bn0 + nw + ni * 16 + lrow;
            int s  = o >> 9;
            int h  = (o >> 6) & 7;
            int dh = o & 63;
            int bh = b * 8 + h;
            if (s == 2) {
                bf16x4 pv;
#pragma unroll
                for (int r = 0; r < 4; r++) pv[r] = (bf16_t)acc[mi][ni][r];
                *(bf16x4*)(Vt + ((size_t)bh * 64 + dh) * 2048 + n) = pv;   // 8B packed
            } else if (s == 0) {
#pragma unroll
                for (int r = 0; r < 4; r++)
                    Q[((size_t)bh * 2048 + n + r) * 64 + dh] = (bf16_t)(acc[mi][ni][r] * QSCALE);
            } else {
#pragma unroll
                for (int r = 0; r < 4; r++)
                    K[((size_t)bh * 2048 + n + r) * 64 + dh] = (bf16_t)acc[mi][ni][r];
            }
        }
    }
}

// -------------------- flash attention --------------------
// R8: K-fragments loaded DIRECTLY from global (perfectly coalesced; K/bh=256 KB
// is L2/L3-resident). Removes K's LDS staging + 32 KB/block-kt of LDS frag reads
// (96 -> 56 KB/block-kt on the LDS pipe). LDS 24 KB -> 6 blocks/CU.
// V stays LDS-staged (its global pattern is 64B segments @ 4KB stride).

__device__ __forceinline__ void stage_v(const bf16_t* __restrict__ vb,
                                        int kt, bf16_t* vsbuf,
                                        int wave, int lane) {
#pragma unroll
    for (int part = 0; part < 2; ++part) {
        int ch  = part * 256 + wave * 64 + lane;   // chunk id 0..511
        int row = ch >> 3, cc = ch & 7;
        int scc = cc ^ (row & 7);                  // swizzled source chunk
        bf16_t* ldst = vsbuf + (size_t)(part * 256 + wave * 64) * 8;  // wave-uniform
        gl2lds16(vb + (size_t)row * 2048 + kt * 64 + scc * 8, ldst);
    }
}

__global__ __launch_bounds__(256) void flash_attn(const bf16_t* __restrict__ Q,   // [32][2048][64], pre-scaled by 0.125*log2e
                                                  const bf16_t* __restrict__ K,   // [32][2048][64]
                                                  const bf16_t* __restrict__ Vt,  // [32][64][2048]
                                                  float* __restrict__ Out)        // [4][2048][512]
{
    __shared__ bf16_t Vs[2][64 * 64];
    __shared__ bf16_t Ps[4][16 * 64];
    // total 24576 B -> 6 blocks/CU

    const int tid  = threadIdx.x;
    const int wave = tid >> 6;
    const int lane = tid & 63;
    const int quad = lane >> 4;
    const int c    = lane & 15;
    const int t7   = c & 7;
    const int qt = blockIdx.x;
    const int bh = blockIdx.y;
    const int b = bh >> 3, h = bh & 7;

    // Q fragments (A-operand: m=lane&15, k=quad*8+j), shifted-query source row
    int qg  = qt * 64 + wave * 16 + c;
    int src = (qg == 0) ? 0 : qg - 1;
    const bf16_t* qbase = Q + ((size_t)bh * 2048 + src) * 64;
    bf16x8 qf0 = *(const bf16x8*)(qbase + quad * 8);
    bf16x8 qf1 = *(const bf16x8*)(qbase + 32 + quad * 8);

    floatx4 o[4];
#pragma unroll
    for (int i = 0; i < 4; i++) o[i] = (floatx4)0.0f;
    float lacc[4] = {0.f, 0.f, 0.f, 0.f};

    const bf16_t* kb = K + ((size_t)bh * 2048) * 64;
    const bf16_t* vb = Vt + ((size_t)bh * 64) * 2048;
    bf16_t* pw = Ps[wave];

    stage_v(vb, 0, Vs[0], wave, lane);

#pragma unroll 1
    for (int kt = 0; kt < 32; ++kt) {
        const int buf = kt & 1;
        __syncthreads();   // V tile kt ready; all waves done reading buf^1
        if (kt < 31)
            stage_v(vb, kt + 1, Vs[buf ^ 1], wave, lane);

        const bf16_t* vs = Vs[buf];

        // S = Qc * K^T; K-fragments direct from global (B-operand: key=sub*16+c,
        // kdim=quad*8+j). Each b128 inst is a coalesced 1 KB wave read, L2-hot.
        floatx4 s[4];
#pragma unroll
        for (int sub = 0; sub < 4; ++sub) {
            const bf16_t* kg = kb + (size_t)(kt * 64 + sub * 16 + c) * 64;
            bf16x8 kf0 = *(const bf16x8*)(kg + quad * 8);
            bf16x8 kf1 = *(const bf16x8*)(kg + 32 + quad * 8);
            floatx4 t = (floatx4)0.0f;
            t = __builtin_amdgcn_mfma_f32_16x16x32_bf16(qf0, kf0, t, 0, 0, 0);
            t = __builtin_amdgcn_mfma_f32_16x16x32_bf16(qf1, kf1, t, 0, 0, 0);
            s[sub] = t;
        }

        // P = exp2(S); in-lane partial row sums; swizzled P write (2-way, free)
#pragma unroll
        for (int sub = 0; sub < 4; ++sub)
#pragma unroll
            for (int r = 0; r < 4; r++) {
                float p = __builtin_amdgcn_exp2f(s[sub][r]);
                lacc[r] += p;
                int row  = quad * 4 + r;
                int col8 = sub * 2 + (c >> 3);
                pw[row * 64 + ((col8 ^ (row & 7)) << 3) + t7] = (bf16_t)p;
            }
        // NO barrier: Ps is per-wave; in-wave DS ordering (lgkmcnt) suffices

        // O += P * V
#pragma unroll
        for (int ki = 0; ki < 2; ++ki) {
            bf16x8 pf = *(const bf16x8*)(pw + c * 64 + (((ki * 4 + quad) ^ t7) << 3));
#pragma unroll
            for (int sub = 0; sub < 4; ++sub) {
                const bf16_t* vrow = vs + (sub * 16 + c) * 64;
                bf16x8 vf = *(const bf16x8*)(vrow + (((ki * 4 + quad) ^ t7) << 3));
                o[sub] = __builtin_amdgcn_mfma_f32_16x16x32_bf16(pf, vf, o[sub], 0, 0, 0);
            }
        }
    }

    // final cross-lane row-sum reduction (16-lane groups)
#pragma unroll
    for (int r = 0; r < 4; r++)
#pragma unroll
        for (int d = 1; d < 16; d <<= 1)
            lacc[r] += __shfl_xor(lacc[r], d, 64);

    // epilogue: out[b][n][h*64 + d] = o / l
    int n0 = qt * 64 + wave * 16 + quad * 4;
    float* ob = Out + (size_t)b * 2048 * 512 + (size_t)h * 64;
#pragma unroll
    for (int r = 0; r < 4; r++) {
        float inv = 1.0f / lacc[r];
        float* orow = ob + (size_t)(n0 + r) * 512;
#pragma unroll
        for (int sub = 0; sub < 4; ++sub)
            orow[sub * 16 + c] = o[sub][r] * inv;
    }
}

// -------------------- launch --------------------
extern "C" void kernel_launch(void* const* d_in, const int* in_sizes, int n_in,
                              void* d_out, int out_size, void* d_ws, size_t ws_size,
                              hipStream_t stream) {
    const float* x = (const float*)d_in[0];   // [4,2048,512]
    const float* w = (const float*)d_in[1];   // [1536,512]
    float* out = (float*)d_out;               // [4,2048,512]

    char* ws = (char*)d_ws;
    bf16_t* q  = (bf16_t*)(ws);               //  8 MB
    bf16_t* k  = (bf16_t*)(ws + 8388608);     //  8 MB
    bf16_t* vt = (bf16_t*)(ws + 16777216);    //  8 MB (end 24 MB)

    qkv_gemm<<<dim3(64, 12), 256, 0, stream>>>(x, w, q, k, vt);
    flash_attn<<<dim3(32, 32), 256, 0, stream>>>(q, k, vt, out);
}

// Round 9
// 177.828 us; speedup vs baseline: 1.2776x; 1.2776x over previous
//
#include <hip/hip_runtime.h>
#include <hip/hip_bf16.h>
#include <stdint.h>

typedef __bf16 bf16_t;
typedef float floatx4 __attribute__((ext_vector_type(4)));
typedef __bf16 bf16x8 __attribute__((ext_vector_type(8)));
typedef __bf16 bf16x4 __attribute__((ext_vector_type(4)));

// scale = DH^-0.5 * log2(e), folded into Q at GEMM epilogue so softmax uses raw exp2
#define QSCALE 0.1803368801111204f

// -------------------- async global->LDS (16B) --------------------
__device__ __forceinline__ void gl2lds16(const bf16_t* g, bf16_t* l) {
    __builtin_amdgcn_global_load_lds(
        (const __attribute__((address_space(1))) unsigned int*)g,
        (__attribute__((address_space(3))) unsigned int*)l,
        16, 0, 0);
}

// -------------------- fp32 -> bf16 convert (x and W fused; R5) --------------------
__global__ __launch_bounds__(256) void convert_kernel(const float* __restrict__ x,
                                                      bf16_t* __restrict__ xb,
                                                      const float* __restrict__ w,
                                                      bf16_t* __restrict__ wb,
                                                      int nx4) {
    int i = blockIdx.x * 256 + threadIdx.x;
    const float* in; bf16_t* out; int j;
    if (i < nx4) { in = x; out = xb; j = i; }
    else         { in = w; out = wb; j = i - nx4; }
    float4 v = ((const float4*)in)[j];
    bf16x4 o;
    o.x = (bf16_t)v.x; o.y = (bf16_t)v.y; o.z = (bf16_t)v.z; o.w = (bf16_t)v.w;
    ((bf16x4*)out)[j] = o;
}

// -------------------- QKV projection GEMM (R5-exact) --------------------
__global__ __launch_bounds__(256) void qkv_gemm(const bf16_t* __restrict__ X,   // [8192][512]
                                                const bf16_t* __restrict__ W,   // [1536][512]
                                                bf16_t* __restrict__ Q,         // [32][2048][64] (pre-scaled)
                                                bf16_t* __restrict__ K,         // [32][2048][64]
                                                bf16_t* __restrict__ Vt)        // [32][64][2048]
{
    __shared__ bf16_t As[128 * 64];
    __shared__ bf16_t Bs[128 * 64];

    const int tid  = threadIdx.x;
    const int wave = tid >> 6;
    const int lane = tid & 63;
    const int quad = lane >> 4;
    const int lrow = lane & 15;
    const int t7g  = lrow & 7;
    const int bm0 = blockIdx.x * 128;
    const int bn0 = blockIdx.y * 128;
    const int mw = (wave >> 1) * 64;
    const int nw = (wave & 1) * 64;
    const int wbase = tid & 192;

    floatx4 acc[4][4];
#pragma unroll
    for (int i = 0; i < 4; i++)
#pragma unroll
        for (int j = 0; j < 4; j++) acc[i][j] = (floatx4)0.0f;

#pragma unroll 1
    for (int kb = 0; kb < 8; ++kb) {
        const int k0 = kb * 64;
        __syncthreads();
#pragma unroll
        for (int r = 0; r < 4; ++r) {
            int c = r * 256 + tid;
            int row = c >> 3, kc = c & 7;
            int skc = kc ^ (row & 7);
            gl2lds16(X + (size_t)(bm0 + row) * 512 + k0 + skc * 8,
                     As + (size_t)(r * 256 + wbase) * 8);
        }
#pragma unroll
        for (int r = 0; r < 4; ++r) {
            int c = r * 256 + tid;
            int row = c >> 3, kc = c & 7;
            int skc = kc ^ (row & 7);
            gl2lds16(W + (size_t)(bn0 + row) * 512 + k0 + skc * 8,
                     Bs + (size_t)(r * 256 + wbase) * 8);
        }
        __syncthreads();
#pragma unroll
        for (int ks = 0; ks < 2; ++ks) {
            bf16x8 af[4], bfr[4];
#pragma unroll
            for (int mi = 0; mi < 4; mi++)
                af[mi] = *(const bf16x8*)(As + (mw + mi * 16 + lrow) * 64 + (((ks * 4 + quad) ^ t7g) << 3));
#pragma unroll
            for (int ni = 0; ni < 4; ni++)
                bfr[ni] = *(const bf16x8*)(Bs + (nw + ni * 16 + lrow) * 64 + (((ks * 4 + quad) ^ t7g) << 3));
#pragma unroll
            for (int mi = 0; mi < 4; mi++)
#pragma unroll
                for (int ni = 0; ni < 4; ni++)
                    acc[mi][ni] = __builtin_amdgcn_mfma_f32_16x16x32_bf16(af[mi], bfr[ni], acc[mi][ni], 0, 0, 0);
        }
    }

#pragma unroll
    for (int mi = 0; mi < 4; mi++) {
        int mbase = bm0 + mw + mi * 16 + quad * 4;
        int b = mbase >> 11, n = mbase & 2047;
#pragma unroll
        for (int ni = 0; ni < 4; ni++) {
            int o = bn0 + nw + ni * 16 + lrow;
            int s  = o >> 9;
            int h  = (o >> 6) & 7;
            int dh = o & 63;
            int bh = b * 8 + h;
            if (s == 2) {
                bf16x4 pv;
#pragma unroll
                for (int r = 0; r < 4; r++) pv[r] = (bf16_t)acc[mi][ni][r];
                *(bf16x4*)(Vt + ((size_t)bh * 64 + dh) * 2048 + n) = pv;
            } else if (s == 0) {
#pragma unroll
                for (int r = 0; r < 4; r++)
                    Q[((size_t)bh * 2048 + n + r) * 64 + dh] = (bf16_t)(acc[mi][ni][r] * QSCALE);
            } else {
#pragma unroll
                for (int r = 0; r < 4; r++)
                    K[((size_t)bh * 2048 + n + r) * 64 + dh] = (bf16_t)acc[mi][ni][r];
            }
        }
    }
}

// -------------------- flash attention --------------------
// R9: key-split wave pairs. Wave = (p = q-half, e = key-half): computes S and
// partial PV for 32 q x its 32 keys. K/V-frag reads hoisted over q-subtiles ->
// per-block-kt LDS traffic 96 -> 64 KB. P stays in the R5 16x64 swizzled layout
// (two 16x32 q-subtiles side by side) -> identical measured-0-conflict patterns.
// O/lacc partials combined across the wave pair once at the end via Ks/Vs reuse.
__device__ __forceinline__ void stage_tile(const bf16_t* __restrict__ kb,
                                           const bf16_t* __restrict__ vb,
                                           int kt, bf16_t* ksbuf, bf16_t* vsbuf,
                                           int wave, int lane) {
#pragma unroll
    for (int part = 0; part < 2; ++part) {
        int ch  = part * 256 + wave * 64 + lane;
        int row = ch >> 3, cc = ch & 7;
        int scc = cc ^ (row & 7);
        bf16_t* ldst = ksbuf + (size_t)(part * 256 + wave * 64) * 8;
        gl2lds16(kb + ((size_t)(kt * 64 + row)) * 64 + scc * 8, ldst);
        bf16_t* ldst2 = vsbuf + (size_t)(part * 256 + wave * 64) * 8;
        gl2lds16(vb + (size_t)row * 2048 + kt * 64 + scc * 8, ldst2);
    }
}

__global__ __launch_bounds__(256) void flash_attn(const bf16_t* __restrict__ Q,   // [32][2048][64], pre-scaled
                                                  const bf16_t* __restrict__ K,   // [32][2048][64]
                                                  const bf16_t* __restrict__ Vt,  // [32][64][2048]
                                                  float* __restrict__ Out)        // [4][2048][512]
{
    __shared__ bf16_t Ks[2][64 * 64];
    __shared__ bf16_t Vs[2][64 * 64];
    __shared__ bf16_t Ps[4][16 * 64];
    // 40960 B -> 4 blocks/CU

    const int tid  = threadIdx.x;
    const int wave = tid >> 6;
    const int lane = tid & 63;
    const int quad = lane >> 4;
    const int c    = lane & 15;
    const int t7   = c & 7;
    const int p = wave >> 1;   // q half within the 64-q block
    const int e = wave & 1;    // key half within each 64-key tile
    const int qt = blockIdx.x;
    const int bh = blockIdx.y;
    const int b = bh >> 3, h = bh & 7;

    // Q fragments for 2 q-subtiles (A-operand: m=lane&15, k=quad*8+j), shifted row
    bf16x8 qf[2][2];
#pragma unroll
    for (int qsub = 0; qsub < 2; qsub++) {
        int qg  = qt * 64 + p * 32 + qsub * 16 + c;
        int src = (qg == 0) ? 0 : qg - 1;
        const bf16_t* qb = Q + ((size_t)bh * 2048 + src) * 64;
        qf[qsub][0] = *(const bf16x8*)(qb + quad * 8);
        qf[qsub][1] = *(const bf16x8*)(qb + 32 + quad * 8);
    }

    floatx4 o[2][4];
#pragma unroll
    for (int qsub = 0; qsub < 2; qsub++)
#pragma unroll
        for (int i = 0; i < 4; i++) o[qsub][i] = (floatx4)0.0f;
    float lacc[2][4] = {{0.f,0.f,0.f,0.f},{0.f,0.f,0.f,0.f}};

    const bf16_t* kb = K + ((size_t)bh * 2048) * 64;
    const bf16_t* vb = Vt + ((size_t)bh * 64) * 2048;
    bf16_t* pw = Ps[wave];

    stage_tile(kb, vb, 0, Ks[0], Vs[0], wave, lane);

#pragma unroll 1
    for (int kt = 0; kt < 32; ++kt) {
        const int buf = kt & 1;
        __syncthreads();   // tile kt ready; all waves done reading buf^1
        if (kt < 31)
            stage_tile(kb, vb, kt + 1, Ks[buf ^ 1], Vs[buf ^ 1], wave, lane);

        const bf16_t* ks = Ks[buf];
        const bf16_t* vs = Vs[buf];

        // S: 32 q x 32 keys (wave's half). K-frags shared across q-subtiles.
        floatx4 s[2][2];
#pragma unroll
        for (int ksub = 0; ksub < 2; ++ksub) {
            const bf16_t* krow = ks + (e * 32 + ksub * 16 + c) * 64;
            bf16x8 kf0 = *(const bf16x8*)(krow + ((quad ^ t7) << 3));
            bf16x8 kf1 = *(const bf16x8*)(krow + (((4 + quad) ^ t7) << 3));
#pragma unroll
            for (int qsub = 0; qsub < 2; ++qsub) {
                floatx4 t = (floatx4)0.0f;
                t = __builtin_amdgcn_mfma_f32_16x16x32_bf16(qf[qsub][0], kf0, t, 0, 0, 0);
                t = __builtin_amdgcn_mfma_f32_16x16x32_bf16(qf[qsub][1], kf1, t, 0, 0, 0);
                s[qsub][ksub] = t;
            }
        }

        // P = exp2(S); P stored as 16x64: col = qsub*32 + ksub*16 + c (R5 swizzle)
#pragma unroll
        for (int qsub = 0; qsub < 2; ++qsub)
#pragma unroll
            for (int ksub = 0; ksub < 2; ++ksub)
#pragma unroll
                for (int r = 0; r < 4; r++) {
                    float pv = __builtin_amdgcn_exp2f(s[qsub][ksub][r]);
                    lacc[qsub][r] += pv;
                    int row = quad * 4 + r;
                    int chl = qsub * 4 + ksub * 2 + (c >> 3);
                    pw[row * 64 + ((chl ^ (row & 7)) << 3) + t7] = (bf16_t)pv;
                }
        // NO barrier: Ps private per wave; in-wave lgkm ordering suffices

        // O += P * V  (kdim = wave's 32 keys; V-frags shared across q-subtiles)
        bf16x8 pf[2];
#pragma unroll
        for (int qsub = 0; qsub < 2; ++qsub)
            pf[qsub] = *(const bf16x8*)(pw + c * 64 + (((qsub * 4 + quad) ^ t7) << 3));
#pragma unroll
        for (int dsub = 0; dsub < 4; ++dsub) {
            const bf16_t* vrow = vs + (dsub * 16 + c) * 64;
            bf16x8 vf = *(const bf16x8*)(vrow + (((e * 4 + quad) ^ t7) << 3));
#pragma unroll
            for (int qsub = 0; qsub < 2; ++qsub)
                o[qsub][dsub] = __builtin_amdgcn_mfma_f32_16x16x32_bf16(pf[qsub], vf, o[qsub][dsub], 0, 0, 0);
        }
    }

    // cross-lane row-sum reduction (16-lane groups)
#pragma unroll
    for (int qsub = 0; qsub < 2; ++qsub)
#pragma unroll
        for (int r = 0; r < 4; r++)
#pragma unroll
            for (int d = 1; d < 16; d <<= 1)
                lacc[qsub][r] += __shfl_xor(lacc[qsub][r], d, 64);

    // cross-parity combine: exchange the qsub != e partials via Ks/Vs reuse
    __syncthreads();                       // all waves done with Ks/Vs
    float* oex = (float*)&Ks[0][0];        // 4 KB per wave
    float* lex = (float*)&Vs[0][0];
    const int pe = e ^ 1;
#pragma unroll
    for (int dsub = 0; dsub < 4; ++dsub)
#pragma unroll
        for (int r = 0; r < 4; r++)
            oex[wave * 1024 + (quad * 4 + r) * 64 + dsub * 16 + c] = o[pe][dsub][r];
#pragma unroll
    for (int r = 0; r < 4; r++)
        lex[wave * 16 + quad * 4 + r] = lacc[pe][r];   // uniform across c lanes
    __syncthreads();

    const int pwav = wave ^ 1;
    int n0 = qt * 64 + p * 32 + e * 16 + quad * 4;
    float* ob = Out + (size_t)b * 2048 * 512 + (size_t)h * 64;
#pragma unroll
    for (int r = 0; r < 4; r++) {
        float lsum = lacc[e][r] + lex[pwav * 16 + quad * 4 + r];
        float inv = 1.0f / lsum;
        float* orow = ob + (size_t)(n0 + r) * 512;
#pragma unroll
        for (int dsub = 0; dsub < 4; ++dsub) {
            float val = o[e][dsub][r] + oex[pwav * 1024 + (quad * 4 + r) * 64 + dsub * 16 + c];
            orow[dsub * 16 + c] = val * inv;
        }
    }
}

// -------------------- launch --------------------
extern "C" void kernel_launch(void* const* d_in, const int* in_sizes, int n_in,
                              void* d_out, int out_size, void* d_ws, size_t ws_size,
                              hipStream_t stream) {
    const float* x = (const float*)d_in[0];   // [4,2048,512]
    const float* w = (const float*)d_in[1];   // [1536,512]
    float* out = (float*)d_out;               // [4,2048,512]

    char* ws = (char*)d_ws;
    bf16_t* xb = (bf16_t*)(ws);                       //  8 MB
    bf16_t* wb = (bf16_t*)(ws + 8388608);             //  1.5 MB
    bf16_t* q  = (bf16_t*)(ws + 9961472);             //  8 MB
    bf16_t* k  = (bf16_t*)(ws + 18350080);            //  8 MB
    bf16_t* vt = (bf16_t*)(ws + 26738688);            //  8 MB (end 33.5 MB)

    convert_kernel<<<4864, 256, 0, stream>>>(x, xb, w, wb, 1048576);
    qkv_gemm<<<dim3(64, 12), 256, 0, stream>>>(xb, wb, q, k, vt);
    flash_attn<<<dim3(32, 32), 256, 0, stream>>>(q, k, vt, out);
}

// Round 10
// 155.594 us; speedup vs baseline: 1.4602x; 1.1429x over previous
//
#include <hip/hip_runtime.h>
#include <hip/hip_bf16.h>
#include <stdint.h>

typedef __bf16 bf16_t;
typedef float floatx4 __attribute__((ext_vector_type(4)));
typedef float floatx16 __attribute__((ext_vector_type(16)));
typedef __bf16 bf16x8 __attribute__((ext_vector_type(8)));
typedef __bf16 bf16x4 __attribute__((ext_vector_type(4)));

// scale = DH^-0.5 * log2(e), folded into Q at GEMM epilogue so softmax uses raw exp2
#define QSCALE 0.1803368801111204f

// -------------------- async global->LDS (16B) --------------------
__device__ __forceinline__ void gl2lds16(const bf16_t* g, bf16_t* l) {
    __builtin_amdgcn_global_load_lds(
        (const __attribute__((address_space(1))) unsigned int*)g,
        (__attribute__((address_space(3))) unsigned int*)l,
        16, 0, 0);
}

// -------------------- fp32 -> bf16 convert (R5-exact) --------------------
__global__ __launch_bounds__(256) void convert_kernel(const float* __restrict__ x,
                                                      bf16_t* __restrict__ xb,
                                                      const float* __restrict__ w,
                                                      bf16_t* __restrict__ wb,
                                                      int nx4) {
    int i = blockIdx.x * 256 + threadIdx.x;
    const float* in; bf16_t* out; int j;
    if (i < nx4) { in = x; out = xb; j = i; }
    else         { in = w; out = wb; j = i - nx4; }
    float4 v = ((const float4*)in)[j];
    bf16x4 o;
    o.x = (bf16_t)v.x; o.y = (bf16_t)v.y; o.z = (bf16_t)v.z; o.w = (bf16_t)v.w;
    ((bf16x4*)out)[j] = o;
}

// -------------------- QKV projection GEMM (R5-exact) --------------------
__global__ __launch_bounds__(256) void qkv_gemm(const bf16_t* __restrict__ X,   // [8192][512]
                                                const bf16_t* __restrict__ W,   // [1536][512]
                                                bf16_t* __restrict__ Q,         // [32][2048][64] (pre-scaled)
                                                bf16_t* __restrict__ K,         // [32][2048][64]
                                                bf16_t* __restrict__ Vt)        // [32][64][2048]
{
    __shared__ bf16_t As[128 * 64];
    __shared__ bf16_t Bs[128 * 64];

    const int tid  = threadIdx.x;
    const int wave = tid >> 6;
    const int lane = tid & 63;
    const int quad = lane >> 4;
    const int lrow = lane & 15;
    const int t7g  = lrow & 7;
    const int bm0 = blockIdx.x * 128;
    const int bn0 = blockIdx.y * 128;
    const int mw = (wave >> 1) * 64;
    const int nw = (wave & 1) * 64;
    const int wbase = tid & 192;

    floatx4 acc[4][4];
#pragma unroll
    for (int i = 0; i < 4; i++)
#pragma unroll
        for (int j = 0; j < 4; j++) acc[i][j] = (floatx4)0.0f;

#pragma unroll 1
    for (int kb = 0; kb < 8; ++kb) {
        const int k0 = kb * 64;
        __syncthreads();
#pragma unroll
        for (int r = 0; r < 4; ++r) {
            int c = r * 256 + tid;
            int row = c >> 3, kc = c & 7;
            int skc = kc ^ (row & 7);
            gl2lds16(X + (size_t)(bm0 + row) * 512 + k0 + skc * 8,
                     As + (size_t)(r * 256 + wbase) * 8);
        }
#pragma unroll
        for (int r = 0; r < 4; ++r) {
            int c = r * 256 + tid;
            int row = c >> 3, kc = c & 7;
            int skc = kc ^ (row & 7);
            gl2lds16(W + (size_t)(bn0 + row) * 512 + k0 + skc * 8,
                     Bs + (size_t)(r * 256 + wbase) * 8);
        }
        __syncthreads();
#pragma unroll
        for (int ks = 0; ks < 2; ++ks) {
            bf16x8 af[4], bfr[4];
#pragma unroll
            for (int mi = 0; mi < 4; mi++)
                af[mi] = *(const bf16x8*)(As + (mw + mi * 16 + lrow) * 64 + (((ks * 4 + quad) ^ t7g) << 3));
#pragma unroll
            for (int ni = 0; ni < 4; ni++)
                bfr[ni] = *(const bf16x8*)(Bs + (nw + ni * 16 + lrow) * 64 + (((ks * 4 + quad) ^ t7g) << 3));
#pragma unroll
            for (int mi = 0; mi < 4; mi++)
#pragma unroll
                for (int ni = 0; ni < 4; ni++)
                    acc[mi][ni] = __builtin_amdgcn_mfma_f32_16x16x32_bf16(af[mi], bfr[ni], acc[mi][ni], 0, 0, 0);
        }
    }

#pragma unroll
    for (int mi = 0; mi < 4; mi++) {
        int mbase = bm0 + mw + mi * 16 + quad * 4;
        int b = mbase >> 11, n = mbase & 2047;
#pragma unroll
        for (int ni = 0; ni < 4; ni++) {
            int o = bn0 + nw + ni * 16 + lrow;
            int s  = o >> 9;
            int h  = (o >> 6) & 7;
            int dh = o & 63;
            int bh = b * 8 + h;
            if (s == 2) {
                bf16x4 pv;
#pragma unroll
                for (int r = 0; r < 4; r++) pv[r] = (bf16_t)acc[mi][ni][r];
                *(bf16x4*)(Vt + ((size_t)bh * 64 + dh) * 2048 + n) = pv;
            } else if (s == 0) {
#pragma unroll
                for (int r = 0; r < 4; r++)
                    Q[((size_t)bh * 2048 + n + r) * 64 + dh] = (bf16_t)(acc[mi][ni][r] * QSCALE);
            } else {
#pragma unroll
                for (int r = 0; r < 4; r++)
                    K[((size_t)bh * 2048 + n + r) * 64 + dh] = (bf16_t)acc[mi][ni][r];
            }
        }
    }
}

// -------------------- flash attention --------------------
// R10: 32x32x16 MFMA, q-tile 128 (4 waves x 32q, each wave FULL 64 keys -- no
// key-split, that failed twice). Per-q LDS traffic 146 -> 82 B (-44%); MFMA
// cyc/FLOP -18%. Grid (16,32); LDS 48 KB; one barrier/kt; P per-wave 32x64
// XOR-chunk swizzled (all patterns <=2-way per 16-lane phase = free).
__device__ __forceinline__ void stage_tile(const bf16_t* __restrict__ kb,
                                           const bf16_t* __restrict__ vb,
                                           int kt, bf16_t* ksbuf, bf16_t* vsbuf,
                                           int wave, int lane) {
#pragma unroll
    for (int part = 0; part < 2; ++part) {
        int ch  = part * 256 + wave * 64 + lane;
        int row = ch >> 3, cc = ch & 7;
        int scc = cc ^ (row & 7);
        bf16_t* ldst = ksbuf + (size_t)(part * 256 + wave * 64) * 8;
        gl2lds16(kb + ((size_t)(kt * 64 + row)) * 64 + scc * 8, ldst);
        bf16_t* ldst2 = vsbuf + (size_t)(part * 256 + wave * 64) * 8;
        gl2lds16(vb + (size_t)row * 2048 + kt * 64 + scc * 8, ldst2);
    }
}

__global__ __launch_bounds__(256) void flash_attn(const bf16_t* __restrict__ Q,   // [32][2048][64], pre-scaled
                                                  const bf16_t* __restrict__ K,   // [32][2048][64]
                                                  const bf16_t* __restrict__ Vt,  // [32][64][2048]
                                                  float* __restrict__ Out)        // [4][2048][512]
{
    __shared__ bf16_t Ks[2][64 * 64];
    __shared__ bf16_t Vs[2][64 * 64];
    __shared__ bf16_t Ps[4][32 * 64];
    // 49152 B -> 3 blocks/CU cap (grid 512 -> 2 resident/CU)

    const int tid  = threadIdx.x;
    const int wave = tid >> 6;
    const int lane = tid & 63;
    const int m    = lane & 31;   // MFMA m/n index
    const int e5   = lane >> 5;   // k-octet select
    const int qt = blockIdx.x;    // 0..15 (128 q rows per block)
    const int bh = blockIdx.y;
    const int b = bh >> 3, h = bh & 7;

    // Q A-fragments: A[m=q][k=dc*16+e5*8+j], shifted-query source row
    int qg  = qt * 128 + wave * 32 + m;
    int src = (qg == 0) ? 0 : qg - 1;
    const bf16_t* qb = Q + ((size_t)bh * 2048 + src) * 64;
    bf16x8 qf[4];
#pragma unroll
    for (int dc = 0; dc < 4; ++dc)
        qf[dc] = *(const bf16x8*)(qb + dc * 16 + e5 * 8);

    floatx16 o[2];
    o[0] = (floatx16)0.0f; o[1] = (floatx16)0.0f;
    float lacc[16];
#pragma unroll
    for (int r = 0; r < 16; r++) lacc[r] = 0.0f;

    const bf16_t* kb = K + ((size_t)bh * 2048) * 64;
    const bf16_t* vb = Vt + ((size_t)bh * 64) * 2048;
    bf16_t* pw = Ps[wave];

    stage_tile(kb, vb, 0, Ks[0], Vs[0], wave, lane);

#pragma unroll 1
    for (int kt = 0; kt < 32; ++kt) {
        const int buf = kt & 1;
        __syncthreads();   // tile kt ready; all waves done reading buf^1
        if (kt < 31)
            stage_tile(kb, vb, kt + 1, Ks[buf ^ 1], Vs[buf ^ 1], wave, lane);

        const bf16_t* ks = Ks[buf];
        const bf16_t* vs = Vs[buf];

        // S + softmax per 32-key half (s regs reused across halves)
#pragma unroll
        for (int kt2 = 0; kt2 < 2; ++kt2) {
            const int key = kt2 * 32 + m;
            const bf16_t* krow = ks + key * 64;
            const int kx = key & 7;
            floatx16 s = (floatx16)0.0f;
#pragma unroll
            for (int dc = 0; dc < 4; ++dc) {
                bf16x8 kf = *(const bf16x8*)(krow + (((dc * 2 + e5) ^ kx) << 3));
                s = __builtin_amdgcn_mfma_f32_32x32x16_bf16(qf[dc], kf, s, 0, 0, 0);
            }
            // exp2 + in-lane row sums + swizzled P write
            // C/D layout: col=lane&31, row=(reg&3)+8*(reg>>2)+4*e5 [m74/m101]
#pragma unroll
            for (int reg = 0; reg < 16; ++reg) {
                float p = __builtin_amdgcn_exp2f(s[reg]);
                lacc[reg] += p;
                int row = (reg & 3) + 8 * (reg >> 2) + 4 * e5;
                int c8  = kt2 * 4 + (m >> 3);
                pw[row * 64 + ((c8 ^ (row & 7)) << 3) + (m & 7)] = (bf16_t)p;
            }
        }
        // NO barrier: Ps private per wave; in-wave lgkm ordering suffices

        // O += P * V  (A = P[32q][64k], B = V[64k][64d] from Vs[d][key])
#pragma unroll
        for (int kc = 0; kc < 4; ++kc) {
            bf16x8 pf = *(const bf16x8*)(pw + m * 64 + (((kc * 2 + e5) ^ (m & 7)) << 3));
#pragma unroll
            for (int dt = 0; dt < 2; ++dt) {
                const int drow = dt * 32 + m;
                bf16x8 vf = *(const bf16x8*)(vs + drow * 64 + (((kc * 2 + e5) ^ (drow & 7)) << 3));
                o[dt] = __builtin_amdgcn_mfma_f32_32x32x16_bf16(pf, vf, o[dt], 0, 0, 0);
            }
        }
    }

    // row-sum reduction across the 32 col-lanes (masks 1..16 stay in e5 half)
#pragma unroll
    for (int reg = 0; reg < 16; ++reg)
#pragma unroll
        for (int d = 1; d < 32; d <<= 1)
            lacc[reg] += __shfl_xor(lacc[reg], d, 64);

    // epilogue: out[b][qrow][h*64 + dt*32 + m] = o/l
    float* ob = Out + (size_t)b * 2048 * 512 + (size_t)h * 64;
#pragma unroll
    for (int reg = 0; reg < 16; ++reg) {
        int qrow = qt * 128 + wave * 32 + (reg & 3) + 8 * (reg >> 2) + 4 * e5;
        float inv = 1.0f / lacc[reg];
        float* orow = ob + (size_t)qrow * 512;
        orow[m]      = o[0][reg] * inv;
        orow[32 + m] = o[1][reg] * inv;
    }
}

// -------------------- launch --------------------
extern "C" void kernel_launch(void* const* d_in, const int* in_sizes, int n_in,
                              void* d_out, int out_size, void* d_ws, size_t ws_size,
                              hipStream_t stream) {
    const float* x = (const float*)d_in[0];   // [4,2048,512]
    const float* w = (const float*)d_in[1];   // [1536,512]
    float* out = (float*)d_out;               // [4,2048,512]

    char* ws = (char*)d_ws;
    bf16_t* xb = (bf16_t*)(ws);                       //  8 MB
    bf16_t* wb = (bf16_t*)(ws + 8388608);             //  1.5 MB
    bf16_t* q  = (bf16_t*)(ws + 9961472);             //  8 MB
    bf16_t* k  = (bf16_t*)(ws + 18350080);            //  8 MB
    bf16_t* vt = (bf16_t*)(ws + 26738688);            //  8 MB (end 33.5 MB)

    convert_kernel<<<4864, 256, 0, stream>>>(x, xb, w, wb, 1048576);
    qkv_gemm<<<dim3(64, 12), 256, 0, stream>>>(xb, wb, q, k, vt);
    flash_attn<<<dim3(16, 32), 256, 0, stream>>>(q, k, vt, out);
}